// Round 2
// baseline (959.319 us; speedup 1.0000x reference)
//
#include <hip/hip_runtime.h>
#include <hip/hip_bf16.h>
#include <stdint.h>

typedef __hip_bfloat16 bf16;
typedef __attribute__((ext_vector_type(8))) short short8;
typedef __attribute__((ext_vector_type(4))) short short4v;
typedef __attribute__((ext_vector_type(4))) float floatx4;

#define D_MODEL 768
#define D_STATE 64
#define D_INNER 1536
#define BATCH   2
#define SEQ     1024
#define M_TOK   (BATCH * SEQ)  // 2048

static __device__ __forceinline__ float bf2f(bf16 v) { return __bfloat162float(v); }

// ---------------------------------------------------------------------------
// fp32 -> bf16 converter (n divisible by 4), vectorized
// ---------------------------------------------------------------------------
__global__ __launch_bounds__(256) void cvt_bf16(
    const float* __restrict__ src, bf16* __restrict__ dst, int n4)
{
  const int i = blockIdx.x * 256 + threadIdx.x;
  if (i >= n4) return;
  const floatx4 v = ((const floatx4*)src)[i];
  short4v o;
  o.x = (short)__bfloat16_as_ushort(__float2bfloat16(v.x));
  o.y = (short)__bfloat16_as_ushort(__float2bfloat16(v.y));
  o.z = (short)__bfloat16_as_ushort(__float2bfloat16(v.z));
  o.w = (short)__bfloat16_as_ushort(__float2bfloat16(v.w));
  ((short4v*)dst)[i] = o;
}

// ---------------------------------------------------------------------------
// GEMM (bt layout): C[M][N] = sum_k A[M][K] * B[N][K], fp32 out
// 128x128 tile, BK=32, 4 waves (2x2 of 64x64), global_load_lds width=16
// A-frag: A[m=lane&15][k=quad*8+j]; B-frag: B[n=lane&15][k=quad*8+j]
// C/D: row = quad*4 + reg, col = lane&15
// ---------------------------------------------------------------------------
__global__ __launch_bounds__(256) void gemm_bt(
    const bf16* __restrict__ A, const bf16* __restrict__ B,
    float* __restrict__ C, int M, int N, int K)
{
  __shared__ __align__(16) short As[128 * 32];
  __shared__ __align__(16) short Bs[128 * 32];
  const int tid  = threadIdx.x;
  const int lane = tid & 63;
  const int quad = lane >> 4;
  const int l15  = lane & 15;
  const int wv   = tid >> 6;
  const int wm   = (wv >> 1) << 6;
  const int wn   = (wv & 1) << 6;
  const long m0  = (long)blockIdx.y * 128;
  const long n0  = (long)blockIdx.x * 128;

  floatx4 acc[4][4];
#pragma unroll
  for (int i = 0; i < 4; ++i)
#pragma unroll
    for (int j = 0; j < 4; ++j)
      acc[i][j] = (floatx4){0.f, 0.f, 0.f, 0.f};

  for (int kt = 0; kt < K; kt += 32) {
    __syncthreads();
#pragma unroll
    for (int i = 0; i < 2; ++i) {
      const int f  = tid + (i << 8);     // 0..511, each chunk = 16B (8 bf16)
      const int fm = f >> 2;             // row within tile
      const int fk = (f & 3) << 3;       // k within tile
      const bf16* ga = A + (m0 + fm) * (long)K + kt + fk;
      const bf16* gb = B + (n0 + fm) * (long)K + kt + fk;
      __builtin_amdgcn_global_load_lds(
          (const __attribute__((address_space(1))) uint32_t*)ga,
          (__attribute__((address_space(3))) uint32_t*)&As[f << 3], 16, 0, 0);
      __builtin_amdgcn_global_load_lds(
          (const __attribute__((address_space(1))) uint32_t*)gb,
          (__attribute__((address_space(3))) uint32_t*)&Bs[f << 3], 16, 0, 0);
    }
    __syncthreads();
    short8 af[4], bf_[4];
#pragma unroll
    for (int i = 0; i < 4; ++i) {
      af[i]  = *(const short8*)&As[(wm + i * 16 + l15) * 32 + (quad << 3)];
      bf_[i] = *(const short8*)&Bs[(wn + i * 16 + l15) * 32 + (quad << 3)];
    }
#pragma unroll
    for (int i = 0; i < 4; ++i)
#pragma unroll
      for (int j = 0; j < 4; ++j)
        acc[i][j] = __builtin_amdgcn_mfma_f32_16x16x32_bf16(af[i], bf_[j], acc[i][j], 0, 0, 0);
  }

#pragma unroll
  for (int i = 0; i < 4; ++i)
#pragma unroll
    for (int j = 0; j < 4; ++j)
#pragma unroll
      for (int r = 0; r < 4; ++r) {
        const long gm = m0 + wm + i * 16 + quad * 4 + r;
        const long gn = n0 + wn + j * 16 + l15;
        C[gm * N + gn] = acc[i][j][r];
      }
}

// ---------------------------------------------------------------------------
// Causal depthwise conv (k=4) + SiLU; also precompute silu(z).
// xz: [2048][3072] fp32 (x_p = cols 0..1535, z = cols 1536..3071)
// ---------------------------------------------------------------------------
__global__ __launch_bounds__(256) void conv_silu(
    const float* __restrict__ xz, const float* __restrict__ conv_w,
    const float* __restrict__ conv_b, bf16* __restrict__ xconv,
    bf16* __restrict__ zsilu)
{
  const int idx = blockIdx.x * 256 + threadIdx.x;  // < 2048*1536
  const int d = idx % D_INNER;
  const int m = idx / D_INNER;
  const int l = m & (SEQ - 1);
  float acc = conv_b[d];
#pragma unroll
  for (int i = 0; i < 4; ++i) {
    const int lp = l + i - 3;
    if (lp >= 0)
      acc = fmaf(xz[(long)(m - 3 + i) * 3072 + d], conv_w[d * 4 + i], acc);
  }
  const float xc = acc / (1.f + __expf(-acc));
  xconv[idx] = __float2bfloat16(xc);
  const float z = xz[(long)m * 3072 + D_INNER + d];
  zsilu[idx] = __float2bfloat16(z / (1.f + __expf(-z)));
}

// ---------------------------------------------------------------------------
// dt_in[m] = dot(xconv[m,:], W_x[0,:]);  dt[m][d] = softplus(dt_in*dt_w[d]+dt_b[d])
// one block (256 threads) per token m
// ---------------------------------------------------------------------------
__global__ __launch_bounds__(256) void dt_kernel(
    const bf16* __restrict__ xconv, const float* __restrict__ Wx0,
    const float* __restrict__ dt_w, const float* __restrict__ dt_b,
    float* __restrict__ dt)
{
  const int m = blockIdx.x;
  const int tid = threadIdx.x;
  const int lane = tid & 63;
  const int wv = tid >> 6;
  float part = 0.f;
  for (int k = tid; k < D_INNER; k += 256)
    part = fmaf(bf2f(xconv[(long)m * D_INNER + k]), Wx0[k], part);
#pragma unroll
  for (int off = 32; off > 0; off >>= 1) part += __shfl_xor(part, off, 64);
  __shared__ float red[4];
  if (lane == 0) red[wv] = part;
  __syncthreads();
  const float dtin = red[0] + red[1] + red[2] + red[3];
  for (int d = tid; d < D_INNER; d += 256) {
    const float xv = fmaf(dtin, dt_w[d], dt_b[d]);
    dt[(long)m * D_INNER + d] = fmaxf(xv, 0.f) + log1pf(__expf(-fabsf(xv)));
  }
}

// ---------------------------------------------------------------------------
// Selective scan. One wave per (b,d); lane = state n. 4 waves/block share b
// (adjacent d) so the coalesced B/C stream is L1-shared.
// xdbl[m][0..63] = B, xdbl[m][64..127] = C (fp32)
// ---------------------------------------------------------------------------
__global__ __launch_bounds__(256) void scan_kernel(
    const float* __restrict__ xdbl, const float* __restrict__ dt,
    const bf16* __restrict__ xconv, const bf16* __restrict__ zsilu,
    const float* __restrict__ A_log, const float* __restrict__ D_param,
    bf16* __restrict__ ygated)
{
  const int lane = threadIdx.x & 63;
  const int wv = threadIdx.x >> 6;
  const int blk = blockIdx.x;           // 0..767
  const int b = blk / 384;
  const int d = (blk % 384) * 4 + wv;
  const float An = -__expf(A_log[lane]);
  const float Dd = D_param[d];
  float h = 0.f;
  const long mbase = (long)b * SEQ;
  for (int l = 0; l < SEQ; ++l) {
    const long m = mbase + l;
    const float dtv = dt[m * D_INNER + d];
    const float xc = bf2f(xconv[m * D_INNER + d]);
    const float Bn = xdbl[m * 128 + lane];
    const float Cn = xdbl[m * 128 + 64 + lane];
    const float dA = __expf(dtv * An);
    h = fmaf(h, dA, dtv * xc * Bn);
    float p = h * Cn;
#pragma unroll
    for (int off = 32; off > 0; off >>= 1) p += __shfl_xor(p, off, 64);
    if (lane == 0) {
      const float yv = fmaf(Dd, xc, p);
      const float zs = bf2f(zsilu[m * D_INNER + d]);
      ygated[m * D_INNER + d] = __float2bfloat16(yv * zs);
    }
  }
}

// ---------------------------------------------------------------------------
extern "C" void kernel_launch(void* const* d_in, const int* in_sizes, int n_in,
                              void* d_out, int out_size, void* d_ws, size_t ws_size,
                              hipStream_t stream)
{
  const float* x       = (const float*)d_in[0];   // [2,1024,768]
  const float* W_in    = (const float*)d_in[1];   // [3072,768]
  const float* conv_w  = (const float*)d_in[2];   // [1536,1,4]
  const float* conv_b  = (const float*)d_in[3];   // [1536]
  const float* W_x     = (const float*)d_in[4];   // [129,1536]
  const float* dt_w    = (const float*)d_in[5];   // [1536,1]
  const float* dt_b    = (const float*)d_in[6];   // [1536]
  const float* A_log   = (const float*)d_in[7];   // [64]
  const float* D_param = (const float*)d_in[8];   // [1536]
  const float* W_out   = (const float*)d_in[9];   // [768,1536]
  float* out = (float*)d_out;                     // [2,1024,768]

  char* ws = (char*)d_ws;
  float* xz     = (float*)(ws);                    // 25,165,824 B
  bf16*  xconv  = (bf16*)(ws + 25165824);          // 6,291,456 B
  bf16*  zsilu  = (bf16*)(ws + 31457280);          // 6,291,456 B
  float* xdbl   = (float*)(ws + 37748736);         // 1,048,576 B
  float* dtbuf  = (float*)(ws + 38797312);         // 12,582,912 B
  bf16*  ygated = (bf16*)(ws + 51380224);          // 6,291,456 B
  bf16*  xbf    = (bf16*)(ws + 57671680);          // 3,145,728 B
  bf16*  Winbf  = (bf16*)(ws + 60817408);          // 4,718,592 B
  bf16*  Wxbf   = (bf16*)(ws + 65536000);          // 393,216 B
  bf16*  Woutbf = (bf16*)(ws + 65929216);          // 2,359,296 B (end 68,288,512)

  // 0) fp32 -> bf16 operand conversions for the MFMA GEMMs
  cvt_bf16<<<(M_TOK * D_MODEL / 4 + 255) / 256, 256, 0, stream>>>(x, xbf, M_TOK * D_MODEL / 4);
  cvt_bf16<<<(2 * D_INNER * D_MODEL / 4 + 255) / 256, 256, 0, stream>>>(W_in, Winbf, 2 * D_INNER * D_MODEL / 4);
  cvt_bf16<<<(128 * D_INNER / 4 + 255) / 256, 256, 0, stream>>>(W_x + D_INNER, Wxbf, 128 * D_INNER / 4);
  cvt_bf16<<<(D_MODEL * D_INNER / 4 + 255) / 256, 256, 0, stream>>>(W_out, Woutbf, D_MODEL * D_INNER / 4);

  // 1) xz = x @ W_in^T   (M=2048, N=3072, K=768) -> fp32
  gemm_bt<<<dim3(3072 / 128, M_TOK / 128), 256, 0, stream>>>(
      xbf, Winbf, xz, M_TOK, 2 * D_INNER, D_MODEL);

  // 2) conv + silu + silu(z)
  conv_silu<<<(M_TOK * D_INNER) / 256, 256, 0, stream>>>(xz, conv_w, conv_b, xconv, zsilu);

  // 3a) dt (fp32)
  dt_kernel<<<M_TOK, 256, 0, stream>>>(xconv, W_x, dt_w, dt_b, dtbuf);

  // 3b) B,C = xconv @ W_x[1:129]^T   (M=2048, N=128, K=1536) -> fp32
  gemm_bt<<<dim3(1, M_TOK / 128), 256, 0, stream>>>(
      xconv, Wxbf, xdbl, M_TOK, 128, D_INNER);

  // 4) selective scan + D skip + silu(z) gate
  scan_kernel<<<768, 256, 0, stream>>>(xdbl, dtbuf, xconv, zsilu, A_log, D_param, ygated);

  // 5) out = ygated @ W_out^T   (M=2048, N=768, K=1536) -> fp32 d_out
  gemm_bt<<<dim3(D_MODEL / 128, M_TOK / 128), 256, 0, stream>>>(
      ygated, Woutbf, out, M_TOK, D_MODEL, D_INNER);
}

// Round 3
// 534.110 us; speedup vs baseline: 1.7961x; 1.7961x over previous
//
#include <hip/hip_runtime.h>
#include <hip/hip_bf16.h>
#include <stdint.h>

typedef __hip_bfloat16 bf16;
typedef __attribute__((ext_vector_type(8))) short short8;
typedef __attribute__((ext_vector_type(4))) short short4v;
typedef __attribute__((ext_vector_type(4))) float floatx4;

#define D_MODEL 768
#define D_STATE 64
#define D_INNER 1536
#define BATCH   2
#define SEQ     1024
#define M_TOK   (BATCH * SEQ)  // 2048
#define CH      32             // scan chunk length

static __device__ __forceinline__ float bf2f(bf16 v) { return __bfloat162float(v); }

// ---------------------------------------------------------------------------
// Fused fp32 -> bf16 conversion of all four GEMM operands (one dispatch).
// Ranges in float4 units: x 393216 | W_in 589824 | W_x[1:129] 49152 | W_out 294912
// ---------------------------------------------------------------------------
__global__ __launch_bounds__(256) void cvt_all(
    const float* __restrict__ x, const float* __restrict__ Win,
    const float* __restrict__ Wx1, const float* __restrict__ Wout,
    bf16* __restrict__ xbf, bf16* __restrict__ winbf,
    bf16* __restrict__ wxbf, bf16* __restrict__ woutbf)
{
  const int i = blockIdx.x * 256 + threadIdx.x;   // < 1327104
  const float* s; bf16* dst; int off;
  if (i < 393216)       { s = x;    dst = xbf;    off = i; }
  else if (i < 983040)  { s = Win;  dst = winbf;  off = i - 393216; }
  else if (i < 1032192) { s = Wx1;  dst = wxbf;   off = i - 983040; }
  else                  { s = Wout; dst = woutbf; off = i - 1032192; }
  const float4 v = ((const float4*)s)[off];
  short4v o;
  o.x = (short)__bfloat16_as_ushort(__float2bfloat16(v.x));
  o.y = (short)__bfloat16_as_ushort(__float2bfloat16(v.y));
  o.z = (short)__bfloat16_as_ushort(__float2bfloat16(v.z));
  o.w = (short)__bfloat16_as_ushort(__float2bfloat16(v.w));
  ((short4v*)dst)[off] = o;
}

// ---------------------------------------------------------------------------
// GEMM (bt layout): C[M][N] = sum_k A[M][K] * B[N][K], fp32 out
// 128x128 tile, BK=32, 4 waves, global_load_lds width=16, mfma 16x16x32 bf16
// ---------------------------------------------------------------------------
__global__ __launch_bounds__(256) void gemm_bt(
    const bf16* __restrict__ A, const bf16* __restrict__ B,
    float* __restrict__ C, int M, int N, int K)
{
  __shared__ __align__(16) short As[128 * 32];
  __shared__ __align__(16) short Bs[128 * 32];
  const int tid  = threadIdx.x;
  const int lane = tid & 63;
  const int quad = lane >> 4;
  const int l15  = lane & 15;
  const int wv   = tid >> 6;
  const int wm   = (wv >> 1) << 6;
  const int wn   = (wv & 1) << 6;
  const long m0  = (long)blockIdx.y * 128;
  const long n0  = (long)blockIdx.x * 128;

  floatx4 acc[4][4];
#pragma unroll
  for (int i = 0; i < 4; ++i)
#pragma unroll
    for (int j = 0; j < 4; ++j)
      acc[i][j] = (floatx4){0.f, 0.f, 0.f, 0.f};

  for (int kt = 0; kt < K; kt += 32) {
    __syncthreads();
#pragma unroll
    for (int i = 0; i < 2; ++i) {
      const int f  = tid + (i << 8);
      const int fm = f >> 2;
      const int fk = (f & 3) << 3;
      const bf16* ga = A + (m0 + fm) * (long)K + kt + fk;
      const bf16* gb = B + (n0 + fm) * (long)K + kt + fk;
      __builtin_amdgcn_global_load_lds(
          (const __attribute__((address_space(1))) uint32_t*)ga,
          (__attribute__((address_space(3))) uint32_t*)&As[f << 3], 16, 0, 0);
      __builtin_amdgcn_global_load_lds(
          (const __attribute__((address_space(1))) uint32_t*)gb,
          (__attribute__((address_space(3))) uint32_t*)&Bs[f << 3], 16, 0, 0);
    }
    __syncthreads();
    short8 af[4], bf_[4];
#pragma unroll
    for (int i = 0; i < 4; ++i) {
      af[i]  = *(const short8*)&As[(wm + i * 16 + l15) * 32 + (quad << 3)];
      bf_[i] = *(const short8*)&Bs[(wn + i * 16 + l15) * 32 + (quad << 3)];
    }
#pragma unroll
    for (int i = 0; i < 4; ++i)
#pragma unroll
      for (int j = 0; j < 4; ++j)
        acc[i][j] = __builtin_amdgcn_mfma_f32_16x16x32_bf16(af[i], bf_[j], acc[i][j], 0, 0, 0);
  }

#pragma unroll
  for (int i = 0; i < 4; ++i)
#pragma unroll
    for (int j = 0; j < 4; ++j)
#pragma unroll
      for (int r = 0; r < 4; ++r) {
        const long gm = m0 + wm + i * 16 + quad * 4 + r;
        const long gn = n0 + wn + j * 16 + l15;
        C[gm * N + gn] = acc[i][j][r];
      }
}

// ---------------------------------------------------------------------------
// Causal depthwise conv (k=4) + SiLU; precompute silu(z); fused partial dot
// for dtin[m] = xconv[m,:]·W_x[0,:] via block reduce + atomicAdd.
// Each block covers 256 consecutive d of one token m (1536 % 256 == 0).
// ---------------------------------------------------------------------------
__global__ __launch_bounds__(256) void conv_silu(
    const float* __restrict__ xz, const float* __restrict__ conv_w,
    const float* __restrict__ conv_b, const float* __restrict__ Wx0,
    bf16* __restrict__ xconv, bf16* __restrict__ zsilu,
    float* __restrict__ dtin)
{
  const int idx = blockIdx.x * 256 + threadIdx.x;  // < 2048*1536
  const int d = idx % D_INNER;
  const int m = idx / D_INNER;
  const int l = m & (SEQ - 1);
  float acc = conv_b[d];
#pragma unroll
  for (int i = 0; i < 4; ++i) {
    const int lp = l + i - 3;
    if (lp >= 0)
      acc = fmaf(xz[(long)(m - 3 + i) * 3072 + d], conv_w[d * 4 + i], acc);
  }
  const float xc = acc / (1.f + __expf(-acc));
  xconv[idx] = __float2bfloat16(xc);
  const float z = xz[(long)m * 3072 + D_INNER + d];
  zsilu[idx] = __float2bfloat16(z / (1.f + __expf(-z)));

  float part = xc * Wx0[d];
#pragma unroll
  for (int off = 32; off > 0; off >>= 1) part += __shfl_xor(part, off, 64);
  __shared__ float red[4];
  if ((threadIdx.x & 63) == 0) red[threadIdx.x >> 6] = part;
  __syncthreads();
  if (threadIdx.x == 0)
    atomicAdd(&dtin[m], red[0] + red[1] + red[2] + red[3]);
}

// ---------------------------------------------------------------------------
// Selective scan v2: 4 states/thread, 16 threads/d, wave = 4 d,
// block = 128 threads = 8 d, grid = 2*192 = 384 blocks.
// Chunked LDS staging (CH=32) with register prefetch of the next chunk.
// ---------------------------------------------------------------------------
__global__ __launch_bounds__(128) void scan_kernel(
    const float* __restrict__ xdbl, const float* __restrict__ dtin,
    const bf16* __restrict__ xconv, const bf16* __restrict__ zsilu,
    const float* __restrict__ A_log, const float* __restrict__ D_param,
    const float* __restrict__ dt_w, const float* __restrict__ dt_b,
    bf16* __restrict__ ygated)
{
  __shared__ float sB[CH][64];    // 8 KB
  __shared__ float sC[CH][64];    // 8 KB
  __shared__ float sdtv[CH][8];   // dt value
  __shared__ float sq[CH][8];     // dt*xc
  __shared__ float sdx[CH][8];    // D*xc
  __shared__ float szs[CH][8];    // silu(z)

  const int tid  = threadIdx.x;     // 0..127
  const int lane = tid & 63;
  const int wv   = tid >> 6;        // 0..1
  const int t16  = lane & 15;       // thread within d
  const int dl   = wv * 4 + (lane >> 4);  // 0..7 local d
  const int b    = blockIdx.x / 192;
  const int d0   = (blockIdx.x % 192) * 8;
  const int d    = d0 + dl;
  const int n0   = t16 * 4;
  const long mb  = (long)b * SEQ;

  float An[4];
#pragma unroll
  for (int i = 0; i < 4; ++i) An[i] = -__expf(A_log[n0 + i]);

  // prefetch registers
  float4 pB[8];
  float pdt[2], pxc[2], pzs[2];

#define ISSUE_LOADS(cc)                                                        \
  {                                                                            \
    const float* src = xdbl + (mb + (cc)) * 128;                               \
    _Pragma("unroll")                                                          \
    for (int j = 0; j < 8; ++j) pB[j] = ((const float4*)src)[tid + j * 128];   \
    _Pragma("unroll")                                                          \
    for (int j = 0; j < 2; ++j) {                                              \
      const int item = tid + j * 128;                                          \
      const int s = item >> 3, dl2 = item & 7;                                 \
      const long m = mb + (cc) + s;                                            \
      pdt[j] = dtin[m];                                                        \
      pxc[j] = bf2f(xconv[m * D_INNER + d0 + dl2]);                            \
      pzs[j] = bf2f(zsilu[m * D_INNER + d0 + dl2]);                            \
    }                                                                          \
  }

#define COMMIT()                                                               \
  {                                                                            \
    _Pragma("unroll")                                                          \
    for (int j = 0; j < 8; ++j) {                                              \
      const int p4 = tid + j * 128;                                            \
      const int m = p4 >> 5;                                                   \
      const int k4 = p4 & 31;                                                  \
      if (k4 < 16) *(float4*)&sB[m][k4 * 4] = pB[j];                           \
      else         *(float4*)&sC[m][(k4 - 16) * 4] = pB[j];                    \
    }                                                                          \
    _Pragma("unroll")                                                          \
    for (int j = 0; j < 2; ++j) {                                              \
      const int item = tid + j * 128;                                          \
      const int s = item >> 3, dl2 = item & 7;                                 \
      const float xv = fmaf(pdt[j], dt_w[d0 + dl2], dt_b[d0 + dl2]);           \
      const float dtv = fmaxf(xv, 0.f) + log1pf(__expf(-fabsf(xv)));           \
      sdtv[s][dl2] = dtv;                                                      \
      sq[s][dl2]   = dtv * pxc[j];                                             \
      sdx[s][dl2]  = D_param[d0 + dl2] * pxc[j];                               \
      szs[s][dl2]  = pzs[j];                                                   \
    }                                                                          \
  }

  ISSUE_LOADS(0);
  COMMIT();
  __syncthreads();

  float h0 = 0.f, h1 = 0.f, h2 = 0.f, h3 = 0.f;

  for (int c = 0; c < SEQ; c += CH) {
    if (c + CH < SEQ) ISSUE_LOADS(c + CH);
#pragma unroll 4
    for (int s = 0; s < CH; ++s) {
      const float4 Bv = *(const float4*)&sB[s][n0];
      const float4 Cv = *(const float4*)&sC[s][n0];
      const float dtv = sdtv[s][dl];
      const float q   = sq[s][dl];
      const float e0 = __expf(dtv * An[0]);
      const float e1 = __expf(dtv * An[1]);
      const float e2 = __expf(dtv * An[2]);
      const float e3 = __expf(dtv * An[3]);
      h0 = fmaf(h0, e0, q * Bv.x);
      h1 = fmaf(h1, e1, q * Bv.y);
      h2 = fmaf(h2, e2, q * Bv.z);
      h3 = fmaf(h3, e3, q * Bv.w);
      float p = fmaf(h3, Cv.w, fmaf(h2, Cv.z, fmaf(h1, Cv.y, h0 * Cv.x)));
      p += __shfl_xor(p, 1, 64);
      p += __shfl_xor(p, 2, 64);
      p += __shfl_xor(p, 4, 64);
      p += __shfl_xor(p, 8, 64);
      if (t16 == 0) {
        const float yv = p + sdx[s][dl];
        ygated[(mb + c + s) * (long)D_INNER + d] = __float2bfloat16(yv * szs[s][dl]);
      }
    }
    if (c + CH < SEQ) {
      __syncthreads();
      COMMIT();
      __syncthreads();
    }
  }
#undef ISSUE_LOADS
#undef COMMIT
}

// ---------------------------------------------------------------------------
extern "C" void kernel_launch(void* const* d_in, const int* in_sizes, int n_in,
                              void* d_out, int out_size, void* d_ws, size_t ws_size,
                              hipStream_t stream)
{
  const float* x       = (const float*)d_in[0];
  const float* W_in    = (const float*)d_in[1];
  const float* conv_w  = (const float*)d_in[2];
  const float* conv_b  = (const float*)d_in[3];
  const float* W_x     = (const float*)d_in[4];
  const float* dt_w    = (const float*)d_in[5];
  const float* dt_b    = (const float*)d_in[6];
  const float* A_log   = (const float*)d_in[7];
  const float* D_param = (const float*)d_in[8];
  const float* W_out   = (const float*)d_in[9];
  float* out = (float*)d_out;

  char* ws = (char*)d_ws;
  float* xz     = (float*)(ws);                    // 25,165,824 B
  bf16*  xconv  = (bf16*)(ws + 25165824);          // 6,291,456 B
  bf16*  zsilu  = (bf16*)(ws + 31457280);          // 6,291,456 B
  float* xdbl   = (float*)(ws + 37748736);         // 1,048,576 B
  float* dtin   = (float*)(ws + 38797312);         // 8,192 B
  bf16*  ygated = (bf16*)(ws + 38805504);          // 6,291,456 B
  bf16*  xbf    = (bf16*)(ws + 45096960);          // 3,145,728 B
  bf16*  Winbf  = (bf16*)(ws + 48242688);          // 4,718,592 B
  bf16*  Wxbf   = (bf16*)(ws + 52961280);          // 393,216 B
  bf16*  Woutbf = (bf16*)(ws + 53354496);          // 2,359,296 B (end 55,713,792)

  // 0) all fp32->bf16 operand conversions in one dispatch
  cvt_all<<<5184, 256, 0, stream>>>(x, W_in, W_x + D_INNER, W_out,
                                    xbf, Winbf, Wxbf, Woutbf);

  // 1) xz = x @ W_in^T
  gemm_bt<<<dim3(3072 / 128, M_TOK / 128), 256, 0, stream>>>(
      xbf, Winbf, xz, M_TOK, 2 * D_INNER, D_MODEL);

  // 2) conv + silu + silu(z) + fused dtin reduction
  hipMemsetAsync(dtin, 0, M_TOK * sizeof(float), stream);
  conv_silu<<<(M_TOK * D_INNER) / 256, 256, 0, stream>>>(
      xz, conv_w, conv_b, W_x, xconv, zsilu, dtin);

  // 3) B,C = xconv @ W_x[1:129]^T
  gemm_bt<<<dim3(1, M_TOK / 128), 256, 0, stream>>>(
      xconv, Wxbf, xdbl, M_TOK, 128, D_INNER);

  // 4) selective scan + D skip + silu(z) gate
  scan_kernel<<<384, 128, 0, stream>>>(xdbl, dtin, xconv, zsilu,
                                       A_log, D_param, dt_w, dt_b, ygated);

  // 5) out = ygated @ W_out^T
  gemm_bt<<<dim3(D_MODEL / 128, M_TOK / 128), 256, 0, stream>>>(
      ygated, Woutbf, out, M_TOK, D_MODEL, D_INNER);
}

// Round 4
// 374.655 us; speedup vs baseline: 2.5605x; 1.4256x over previous
//
#include <hip/hip_runtime.h>
#include <hip/hip_bf16.h>
#include <stdint.h>

typedef __hip_bfloat16 bf16;
typedef __attribute__((ext_vector_type(8))) short short8;
typedef __attribute__((ext_vector_type(4))) short short4v;
typedef __attribute__((ext_vector_type(4))) float floatx4;

#define D_MODEL 768
#define D_STATE 64
#define D_INNER 1536
#define BATCH   2
#define SEQ     1024
#define M_TOK   (BATCH * SEQ)  // 2048
#define CH      32             // LDS stage length
#define CHUNK   64             // scan chunk length
#define NCHUNK  (SEQ / CHUNK)  // 16

static __device__ __forceinline__ float bf2f(bf16 v) { return __bfloat162float(v); }

// ---------------------------------------------------------------------------
// Fused fp32 -> bf16 conversion of all four GEMM operands (one dispatch).
// ---------------------------------------------------------------------------
__global__ __launch_bounds__(256) void cvt_all(
    const float* __restrict__ x, const float* __restrict__ Win,
    const float* __restrict__ Wx1, const float* __restrict__ Wout,
    bf16* __restrict__ xbf, bf16* __restrict__ winbf,
    bf16* __restrict__ wxbf, bf16* __restrict__ woutbf)
{
  const int i = blockIdx.x * 256 + threadIdx.x;   // < 1327104
  const float* s; bf16* dst; int off;
  if (i < 393216)       { s = x;    dst = xbf;    off = i; }
  else if (i < 983040)  { s = Win;  dst = winbf;  off = i - 393216; }
  else if (i < 1032192) { s = Wx1;  dst = wxbf;   off = i - 983040; }
  else                  { s = Wout; dst = woutbf; off = i - 1032192; }
  const float4 v = ((const float4*)s)[off];
  short4v o;
  o.x = (short)__bfloat16_as_ushort(__float2bfloat16(v.x));
  o.y = (short)__bfloat16_as_ushort(__float2bfloat16(v.y));
  o.z = (short)__bfloat16_as_ushort(__float2bfloat16(v.z));
  o.w = (short)__bfloat16_as_ushort(__float2bfloat16(v.w));
  ((short4v*)dst)[off] = o;
}

// ---------------------------------------------------------------------------
// GEMM (bt layout): C[M][N] = sum_k A[M][K] * B[N][K], fp32 out
// ---------------------------------------------------------------------------
__global__ __launch_bounds__(256) void gemm_bt(
    const bf16* __restrict__ A, const bf16* __restrict__ B,
    float* __restrict__ C, int M, int N, int K)
{
  __shared__ __align__(16) short As[128 * 32];
  __shared__ __align__(16) short Bs[128 * 32];
  const int tid  = threadIdx.x;
  const int lane = tid & 63;
  const int quad = lane >> 4;
  const int l15  = lane & 15;
  const int wv   = tid >> 6;
  const int wm   = (wv >> 1) << 6;
  const int wn   = (wv & 1) << 6;
  const long m0  = (long)blockIdx.y * 128;
  const long n0  = (long)blockIdx.x * 128;

  floatx4 acc[4][4];
#pragma unroll
  for (int i = 0; i < 4; ++i)
#pragma unroll
    for (int j = 0; j < 4; ++j)
      acc[i][j] = (floatx4){0.f, 0.f, 0.f, 0.f};

  for (int kt = 0; kt < K; kt += 32) {
    __syncthreads();
#pragma unroll
    for (int i = 0; i < 2; ++i) {
      const int f  = tid + (i << 8);
      const int fm = f >> 2;
      const int fk = (f & 3) << 3;
      const bf16* ga = A + (m0 + fm) * (long)K + kt + fk;
      const bf16* gb = B + (n0 + fm) * (long)K + kt + fk;
      __builtin_amdgcn_global_load_lds(
          (const __attribute__((address_space(1))) uint32_t*)ga,
          (__attribute__((address_space(3))) uint32_t*)&As[f << 3], 16, 0, 0);
      __builtin_amdgcn_global_load_lds(
          (const __attribute__((address_space(1))) uint32_t*)gb,
          (__attribute__((address_space(3))) uint32_t*)&Bs[f << 3], 16, 0, 0);
    }
    __syncthreads();
    short8 af[4], bf_[4];
#pragma unroll
    for (int i = 0; i < 4; ++i) {
      af[i]  = *(const short8*)&As[(wm + i * 16 + l15) * 32 + (quad << 3)];
      bf_[i] = *(const short8*)&Bs[(wn + i * 16 + l15) * 32 + (quad << 3)];
    }
#pragma unroll
    for (int i = 0; i < 4; ++i)
#pragma unroll
      for (int j = 0; j < 4; ++j)
        acc[i][j] = __builtin_amdgcn_mfma_f32_16x16x32_bf16(af[i], bf_[j], acc[i][j], 0, 0, 0);
  }

#pragma unroll
  for (int i = 0; i < 4; ++i)
#pragma unroll
    for (int j = 0; j < 4; ++j)
#pragma unroll
      for (int r = 0; r < 4; ++r) {
        const long gm = m0 + wm + i * 16 + quad * 4 + r;
        const long gn = n0 + wn + j * 16 + l15;
        C[gm * N + gn] = acc[i][j][r];
      }
}

// ---------------------------------------------------------------------------
// Causal depthwise conv (k=4) + SiLU; precompute silu(z); fused partial dot
// for dtin[m] = xconv[m,:]·W_x[0,:] via block reduce + atomicAdd.
// ---------------------------------------------------------------------------
__global__ __launch_bounds__(256) void conv_silu(
    const float* __restrict__ xz, const float* __restrict__ conv_w,
    const float* __restrict__ conv_b, const float* __restrict__ Wx0,
    bf16* __restrict__ xconv, bf16* __restrict__ zsilu,
    float* __restrict__ dtin)
{
  const int idx = blockIdx.x * 256 + threadIdx.x;  // < 2048*1536
  const int d = idx % D_INNER;
  const int m = idx / D_INNER;
  const int l = m & (SEQ - 1);
  float acc = conv_b[d];
#pragma unroll
  for (int i = 0; i < 4; ++i) {
    const int lp = l + i - 3;
    if (lp >= 0)
      acc = fmaf(xz[(long)(m - 3 + i) * 3072 + d], conv_w[d * 4 + i], acc);
  }
  const float xc = acc / (1.f + __expf(-acc));
  xconv[idx] = __float2bfloat16(xc);
  const float z = xz[(long)m * 3072 + D_INNER + d];
  zsilu[idx] = __float2bfloat16(z / (1.f + __expf(-z)));

  float part = xc * Wx0[d];
#pragma unroll
  for (int off = 32; off > 0; off >>= 1) part += __shfl_xor(part, off, 64);
  __shared__ float red[4];
  if ((threadIdx.x & 63) == 0) red[threadIdx.x >> 6] = part;
  __syncthreads();
  if (threadIdx.x == 0)
    atomicAdd(&dtin[m], red[0] + red[1] + red[2] + red[3]);
}

// ---------------------------------------------------------------------------
// Chunked selective scan, pass 1 (FINAL=false) and pass 3 (FINAL=true).
// Block: 128 thr = 8 d x 16 thr/d x 4 states/thr. Grid: (192 dgroups, 16 chunks, 2 b).
// Pass1: local scan from h=0 over 64 steps -> H (final state), Q = exp(An*sum dt).
// Pass3: scan from h=S_c (stored in Hbuf by scan_link) -> y outputs.
// ---------------------------------------------------------------------------
template <bool FINAL>
__global__ __launch_bounds__(128) void scan_chunk(
    const float* __restrict__ xdbl, const float* __restrict__ dtin,
    const bf16* __restrict__ xconv, const bf16* __restrict__ zsilu,
    const float* __restrict__ A_log, const float* __restrict__ D_param,
    const float* __restrict__ dt_w, const float* __restrict__ dt_b,
    float* __restrict__ Hbuf, float* __restrict__ Qbuf,
    bf16* __restrict__ ygated)
{
  __shared__ float sB[CH][64];
  __shared__ float sC[CH][64];
  __shared__ float sdtv[CH][8];
  __shared__ float sq[CH][8];
  __shared__ float sdx[CH][8];
  __shared__ float szs[CH][8];

  const int tid  = threadIdx.x;
  const int lane = tid & 63;
  const int wv   = tid >> 6;
  const int t16  = lane & 15;
  const int dl   = wv * 4 + (lane >> 4);     // 0..7
  const int dg   = blockIdx.x;               // 0..191
  const int c    = blockIdx.y;               // 0..15
  const int b    = blockIdx.z;               // 0..1
  const int d0   = dg * 8;
  const int d    = d0 + dl;
  const int n0   = t16 * 4;
  const long mb  = (long)b * SEQ;
  const int c0   = c * CHUNK;

  float An[4];
#pragma unroll
  for (int i = 0; i < 4; ++i) An[i] = -__expf(A_log[n0 + i]);

  float4 pB[8];
  float pdt[2], pxc[2], pzs[2];

#define ISSUE_LOADS(cc)                                                        \
  {                                                                            \
    const float* src = xdbl + (mb + (cc)) * 128;                               \
    _Pragma("unroll")                                                          \
    for (int j = 0; j < 8; ++j) pB[j] = ((const float4*)src)[tid + j * 128];   \
    _Pragma("unroll")                                                          \
    for (int j = 0; j < 2; ++j) {                                              \
      const int item = tid + j * 128;                                          \
      const int s = item >> 3, dl2 = item & 7;                                 \
      const long m = mb + (cc) + s;                                            \
      pdt[j] = dtin[m];                                                        \
      pxc[j] = bf2f(xconv[m * D_INNER + d0 + dl2]);                            \
      if constexpr (FINAL) pzs[j] = bf2f(zsilu[m * D_INNER + d0 + dl2]);       \
    }                                                                          \
  }

#define COMMIT()                                                               \
  {                                                                            \
    _Pragma("unroll")                                                          \
    for (int j = 0; j < 8; ++j) {                                              \
      const int p4 = tid + j * 128;                                            \
      const int m = p4 >> 5;                                                   \
      const int k4 = p4 & 31;                                                  \
      if (k4 < 16) *(float4*)&sB[m][k4 * 4] = pB[j];                           \
      else         *(float4*)&sC[m][(k4 - 16) * 4] = pB[j];                    \
    }                                                                          \
    _Pragma("unroll")                                                          \
    for (int j = 0; j < 2; ++j) {                                              \
      const int item = tid + j * 128;                                          \
      const int s = item >> 3, dl2 = item & 7;                                 \
      const float xv = fmaf(pdt[j], dt_w[d0 + dl2], dt_b[d0 + dl2]);           \
      const float dtv = fmaxf(xv, 0.f) + log1pf(__expf(-fabsf(xv)));           \
      sdtv[s][dl2] = dtv;                                                      \
      sq[s][dl2]   = dtv * pxc[j];                                             \
      if constexpr (FINAL) {                                                   \
        sdx[s][dl2] = D_param[d0 + dl2] * pxc[j];                              \
        szs[s][dl2] = pzs[j];                                                  \
      }                                                                        \
    }                                                                          \
  }

  ISSUE_LOADS(c0);
  COMMIT();
  __syncthreads();

  const long base = (((long)b * NCHUNK + c) * D_INNER + d) * 64 + n0;
  float h0, h1, h2, h3;
  if constexpr (FINAL) {
    const float4 S = *(const float4*)&Hbuf[base];
    h0 = S.x; h1 = S.y; h2 = S.z; h3 = S.w;
  } else {
    h0 = h1 = h2 = h3 = 0.f;
  }
  float Tsum = 0.f;

  for (int cs = 0; cs < CHUNK; cs += CH) {
    if (cs + CH < CHUNK) ISSUE_LOADS(c0 + cs + CH);
#pragma unroll 4
    for (int s = 0; s < CH; ++s) {
      const float4 Bv = *(const float4*)&sB[s][n0];
      const float dtv = sdtv[s][dl];
      const float q   = sq[s][dl];
      const float e0 = __expf(dtv * An[0]);
      const float e1 = __expf(dtv * An[1]);
      const float e2 = __expf(dtv * An[2]);
      const float e3 = __expf(dtv * An[3]);
      h0 = fmaf(h0, e0, q * Bv.x);
      h1 = fmaf(h1, e1, q * Bv.y);
      h2 = fmaf(h2, e2, q * Bv.z);
      h3 = fmaf(h3, e3, q * Bv.w);
      if constexpr (FINAL) {
        const float4 Cv = *(const float4*)&sC[s][n0];
        float p = fmaf(h3, Cv.w, fmaf(h2, Cv.z, fmaf(h1, Cv.y, h0 * Cv.x)));
        p += __shfl_xor(p, 1, 64);
        p += __shfl_xor(p, 2, 64);
        p += __shfl_xor(p, 4, 64);
        p += __shfl_xor(p, 8, 64);
        if (t16 == 0) {
          const float yv = p + sdx[s][dl];
          ygated[(mb + c0 + cs + s) * (long)D_INNER + d] =
              __float2bfloat16(yv * szs[s][dl]);
        }
      } else {
        Tsum += dtv;
      }
    }
    if (cs + CH < CHUNK) {
      __syncthreads();
      COMMIT();
      __syncthreads();
    }
  }

  if constexpr (!FINAL) {
    *(float4*)&Hbuf[base] = (float4){h0, h1, h2, h3};
    const float4 Qv = {__expf(An[0] * Tsum), __expf(An[1] * Tsum),
                       __expf(An[2] * Tsum), __expf(An[3] * Tsum)};
    *(float4*)&Qbuf[base] = Qv;
  }
#undef ISSUE_LOADS
#undef COMMIT
}

// ---------------------------------------------------------------------------
// Inter-chunk linkage: S_0 = 0; S_c = H_{c-1} + Q_{c-1} * S_{c-1}.
// In-place: after this kernel Hbuf[c] holds S_c. One thread per (b, d, n/4).
// ---------------------------------------------------------------------------
__global__ __launch_bounds__(256) void scan_link(
    float* __restrict__ H, const float* __restrict__ Q)
{
  const int t = blockIdx.x * 256 + threadIdx.x;  // < 49152
  const int b = t / 24576;
  const int dn4 = t % 24576;
  float4* H4 = (float4*)H;
  const float4* Q4 = (const float4*)Q;
  float4 S = {0.f, 0.f, 0.f, 0.f};
#pragma unroll
  for (int c = 0; c < NCHUNK; ++c) {
    const long i = (long)(b * NCHUNK + c) * 24576 + dn4;
    const float4 Hc = H4[i];
    const float4 Qc = Q4[i];
    H4[i] = S;
    S.x = fmaf(Qc.x, S.x, Hc.x);
    S.y = fmaf(Qc.y, S.y, Hc.y);
    S.z = fmaf(Qc.z, S.z, Hc.z);
    S.w = fmaf(Qc.w, S.w, Hc.w);
  }
}

// ---------------------------------------------------------------------------
extern "C" void kernel_launch(void* const* d_in, const int* in_sizes, int n_in,
                              void* d_out, int out_size, void* d_ws, size_t ws_size,
                              hipStream_t stream)
{
  const float* x       = (const float*)d_in[0];
  const float* W_in    = (const float*)d_in[1];
  const float* conv_w  = (const float*)d_in[2];
  const float* conv_b  = (const float*)d_in[3];
  const float* W_x     = (const float*)d_in[4];
  const float* dt_w    = (const float*)d_in[5];
  const float* dt_b    = (const float*)d_in[6];
  const float* A_log   = (const float*)d_in[7];
  const float* D_param = (const float*)d_in[8];
  const float* W_out   = (const float*)d_in[9];
  float* out = (float*)d_out;

  char* ws = (char*)d_ws;
  float* xz     = (float*)(ws);                    // 25,165,824 B (dead after conv)
  float* Hbuf   = (float*)(ws);                    // 12,582,912 B (overlays xz)
  float* Qbuf   = (float*)(ws + 12582912);         // 12,582,912 B (overlays xz)
  bf16*  xconv  = (bf16*)(ws + 25165824);          // 6,291,456 B
  bf16*  zsilu  = (bf16*)(ws + 31457280);          // 6,291,456 B
  float* xdbl   = (float*)(ws + 37748736);         // 1,048,576 B
  float* dtin   = (float*)(ws + 38797312);         // 8,192 B
  bf16*  ygated = (bf16*)(ws + 38805504);          // 6,291,456 B
  bf16*  xbf    = (bf16*)(ws + 45096960);          // 3,145,728 B
  bf16*  Winbf  = (bf16*)(ws + 48242688);          // 4,718,592 B
  bf16*  Wxbf   = (bf16*)(ws + 52961280);          // 393,216 B
  bf16*  Woutbf = (bf16*)(ws + 53354496);          // 2,359,296 B (end 55,713,792)

  // 0) all fp32->bf16 operand conversions in one dispatch
  cvt_all<<<5184, 256, 0, stream>>>(x, W_in, W_x + D_INNER, W_out,
                                    xbf, Winbf, Wxbf, Woutbf);

  // 1) xz = x @ W_in^T
  gemm_bt<<<dim3(3072 / 128, M_TOK / 128), 256, 0, stream>>>(
      xbf, Winbf, xz, M_TOK, 2 * D_INNER, D_MODEL);

  // 2) conv + silu + silu(z) + fused dtin reduction
  hipMemsetAsync(dtin, 0, M_TOK * sizeof(float), stream);
  conv_silu<<<(M_TOK * D_INNER) / 256, 256, 0, stream>>>(
      xz, conv_w, conv_b, W_x, xconv, zsilu, dtin);

  // 3) B,C = xconv @ W_x[1:129]^T
  gemm_bt<<<dim3(1, M_TOK / 128), 256, 0, stream>>>(
      xconv, Wxbf, xdbl, M_TOK, 128, D_INNER);

  // 4) chunked selective scan (3 passes); H/Q overlay the dead xz region
  scan_chunk<false><<<dim3(192, NCHUNK, 2), 128, 0, stream>>>(
      xdbl, dtin, xconv, nullptr, A_log, nullptr, dt_w, dt_b,
      Hbuf, Qbuf, nullptr);
  scan_link<<<192, 256, 0, stream>>>(Hbuf, Qbuf);
  scan_chunk<true><<<dim3(192, NCHUNK, 2), 128, 0, stream>>>(
      xdbl, dtin, xconv, zsilu, A_log, D_param, dt_w, dt_b,
      Hbuf, nullptr, ygated);

  // 5) out = ygated @ W_out^T
  gemm_bt<<<dim3(D_MODEL / 128, M_TOK / 128), 256, 0, stream>>>(
      ygated, Woutbf, out, M_TOK, D_MODEL, D_INNER);
}

// Round 5
// 266.134 us; speedup vs baseline: 3.6046x; 1.4078x over previous
//
#include <hip/hip_runtime.h>
#include <hip/hip_bf16.h>
#include <stdint.h>

typedef __hip_bfloat16 bf16;
typedef __attribute__((ext_vector_type(8))) short short8;
typedef __attribute__((ext_vector_type(4))) short short4v;
typedef __attribute__((ext_vector_type(4))) float floatx4;

#define D_MODEL 768
#define D_STATE 64
#define D_INNER 1536
#define BATCH   2
#define SEQ     1024
#define M_TOK   (BATCH * SEQ)  // 2048
#define CH      32             // LDS stage length
#define CHUNK   64             // scan chunk length
#define NCHUNK  (SEQ / CHUNK)  // 16

static __device__ __forceinline__ float bf2f(bf16 v) { return __bfloat162float(v); }

// ---------------------------------------------------------------------------
// Fused fp32 -> bf16 conversion of all four GEMM operands (one dispatch).
// ---------------------------------------------------------------------------
__global__ __launch_bounds__(256) void cvt_all(
    const float* __restrict__ x, const float* __restrict__ Win,
    const float* __restrict__ Wx1, const float* __restrict__ Wout,
    bf16* __restrict__ xbf, bf16* __restrict__ winbf,
    bf16* __restrict__ wxbf, bf16* __restrict__ woutbf)
{
  const int i = blockIdx.x * 256 + threadIdx.x;   // < 1327104
  const float* s; bf16* dst; int off;
  if (i < 393216)       { s = x;    dst = xbf;    off = i; }
  else if (i < 983040)  { s = Win;  dst = winbf;  off = i - 393216; }
  else if (i < 1032192) { s = Wx1;  dst = wxbf;   off = i - 983040; }
  else                  { s = Wout; dst = woutbf; off = i - 1032192; }
  const float4 v = ((const float4*)s)[off];
  short4v o;
  o.x = (short)__bfloat16_as_ushort(__float2bfloat16(v.x));
  o.y = (short)__bfloat16_as_ushort(__float2bfloat16(v.y));
  o.z = (short)__bfloat16_as_ushort(__float2bfloat16(v.z));
  o.w = (short)__bfloat16_as_ushort(__float2bfloat16(v.w));
  ((short4v*)dst)[off] = o;
}

// ---------------------------------------------------------------------------
// GEMM (bt layout): C[M][N] = sum_k A[M][K] * B[N][K].
// Templated tile: BM x BN, BK=32, 4 waves in 2x2. SPLITK>1 -> fp32 atomicAdd.
// ---------------------------------------------------------------------------
template <int BM, int BN, int SPLITK, typename OutT>
__global__ __launch_bounds__(256) void gemm_bt(
    const bf16* __restrict__ A, const bf16* __restrict__ B,
    OutT* __restrict__ C, int M, int N, int K)
{
  __shared__ __align__(16) short As[BM * 32];
  __shared__ __align__(16) short Bs[BN * 32];
  constexpr int WM = BM / 2, WN = BN / 2;
  constexpr int IM = WM / 16, JN = WN / 16;
  constexpr int LA = BM / 64, LB = BN / 64;
  const int tid  = threadIdx.x;
  const int lane = tid & 63;
  const int quad = lane >> 4;
  const int l15  = lane & 15;
  const int wv   = tid >> 6;
  const int wm   = (wv >> 1) * WM;
  const int wn   = (wv & 1) * WN;
  const long m0  = (long)blockIdx.y * BM;
  const long n0  = (long)blockIdx.x * BN;
  const int kpb  = K / SPLITK;
  const int kbeg = blockIdx.z * kpb;
  const int kend = kbeg + kpb;

  floatx4 acc[IM][JN];
#pragma unroll
  for (int i = 0; i < IM; ++i)
#pragma unroll
    for (int j = 0; j < JN; ++j)
      acc[i][j] = (floatx4){0.f, 0.f, 0.f, 0.f};

  for (int kt = kbeg; kt < kend; kt += 32) {
    __syncthreads();
#pragma unroll
    for (int i = 0; i < LA; ++i) {
      const int f  = tid + (i << 8);
      const int fm = f >> 2;
      const int fk = (f & 3) << 3;
      const bf16* ga = A + (m0 + fm) * (long)K + kt + fk;
      __builtin_amdgcn_global_load_lds(
          (const __attribute__((address_space(1))) uint32_t*)ga,
          (__attribute__((address_space(3))) uint32_t*)&As[f << 3], 16, 0, 0);
    }
#pragma unroll
    for (int i = 0; i < LB; ++i) {
      const int f  = tid + (i << 8);
      const int fm = f >> 2;
      const int fk = (f & 3) << 3;
      const bf16* gb = B + (n0 + fm) * (long)K + kt + fk;
      __builtin_amdgcn_global_load_lds(
          (const __attribute__((address_space(1))) uint32_t*)gb,
          (__attribute__((address_space(3))) uint32_t*)&Bs[f << 3], 16, 0, 0);
    }
    __syncthreads();
    short8 af[IM], bf_[JN];
#pragma unroll
    for (int i = 0; i < IM; ++i)
      af[i]  = *(const short8*)&As[(wm + i * 16 + l15) * 32 + (quad << 3)];
#pragma unroll
    for (int j = 0; j < JN; ++j)
      bf_[j] = *(const short8*)&Bs[(wn + j * 16 + l15) * 32 + (quad << 3)];
#pragma unroll
    for (int i = 0; i < IM; ++i)
#pragma unroll
      for (int j = 0; j < JN; ++j)
        acc[i][j] = __builtin_amdgcn_mfma_f32_16x16x32_bf16(af[i], bf_[j], acc[i][j], 0, 0, 0);
  }

#pragma unroll
  for (int i = 0; i < IM; ++i)
#pragma unroll
    for (int j = 0; j < JN; ++j)
#pragma unroll
      for (int r = 0; r < 4; ++r) {
        const long gm = m0 + wm + i * 16 + quad * 4 + r;
        const long gn = n0 + wn + j * 16 + l15;
        const float v = acc[i][j][r];
        if constexpr (SPLITK > 1)
          atomicAdd((float*)&C[gm * N + gn], v);
        else if constexpr (sizeof(OutT) == 2)
          C[gm * N + gn] = __float2bfloat16(v);
        else
          C[gm * N + gn] = v;
      }
}

// ---------------------------------------------------------------------------
// Causal depthwise conv (k=4) + SiLU; precompute silu(z); fused partial dot
// for dtin[m] = xconv[m,:]·W_x[0,:] via block reduce + atomicAdd.
// xz is bf16 [2048][3072].
// ---------------------------------------------------------------------------
__global__ __launch_bounds__(256) void conv_silu(
    const bf16* __restrict__ xz, const float* __restrict__ conv_w,
    const float* __restrict__ conv_b, const float* __restrict__ Wx0,
    bf16* __restrict__ xconv, bf16* __restrict__ zsilu,
    float* __restrict__ dtin)
{
  const int idx = blockIdx.x * 256 + threadIdx.x;  // < 2048*1536
  const int d = idx % D_INNER;
  const int m = idx / D_INNER;
  const int l = m & (SEQ - 1);
  float acc = conv_b[d];
#pragma unroll
  for (int i = 0; i < 4; ++i) {
    const int lp = l + i - 3;
    if (lp >= 0)
      acc = fmaf(bf2f(xz[(long)(m - 3 + i) * 3072 + d]), conv_w[d * 4 + i], acc);
  }
  const float xc = acc / (1.f + __expf(-acc));
  xconv[idx] = __float2bfloat16(xc);
  const float z = bf2f(xz[(long)m * 3072 + D_INNER + d]);
  zsilu[idx] = __float2bfloat16(z / (1.f + __expf(-z)));

  float part = xc * Wx0[d];
#pragma unroll
  for (int off = 32; off > 0; off >>= 1) part += __shfl_xor(part, off, 64);
  __shared__ float red[4];
  if ((threadIdx.x & 63) == 0) red[threadIdx.x >> 6] = part;
  __syncthreads();
  if (threadIdx.x == 0)
    atomicAdd(&dtin[m], red[0] + red[1] + red[2] + red[3]);
}

// ---------------------------------------------------------------------------
// Chunked selective scan. Block = 1024 thr = 64 d x 16 lanes/d; 4 states/lane.
// Grid (24 dgroups, 16 chunks, 2 b) = 768 blocks.
// Pass1 (FINAL=false): local scan h=0 -> Hbuf (chunk-final state), Tbuf (sum dt).
// Pass3 (FINAL=true):  scan from S_c (in Hbuf after scan_link) -> ygated.
// Dynamic LDS: pass1 sB 8K + sp2 16K = 24K; pass3 sB 8K + sC 8K + sp4 32K + sy 4K = 52K.
// ---------------------------------------------------------------------------
template <bool FINAL>
__global__ __launch_bounds__(1024, 8) void scan_chunk(
    const float* __restrict__ xdbl, const float* __restrict__ dtin,
    const bf16* __restrict__ xconv, const bf16* __restrict__ zsilu,
    const float* __restrict__ A_log, const float* __restrict__ D_param,
    const float* __restrict__ dt_w, const float* __restrict__ dt_b,
    float* __restrict__ Hbuf, float* __restrict__ Tbuf,
    bf16* __restrict__ ygated)
{
  extern __shared__ __align__(16) char smem[];
  float*  sB  = (float*)smem;                    // [CH][64]
  float*  sC  = (float*)(smem + 8192);           // [CH][64]   (FINAL)
  float4* sp4 = (float4*)(smem + 16384);         // [CH][64]   (FINAL: dtv,q,dx,zs)
  bf16*   sy  = (bf16*)(smem + 49152);           // [CH][64]   (FINAL)
  float2* sp2 = (float2*)(smem + 8192);          // [CH][64]   (!FINAL: dtv,q)

  const int tid  = threadIdx.x;                  // 0..1023
  const int t16  = tid & 15;
  const int dl   = tid >> 4;                     // 0..63
  const int dg   = blockIdx.x;                   // 0..23
  const int c    = blockIdx.y;                   // 0..15
  const int b    = blockIdx.z;                   // 0..1
  const int d0   = dg * 64;
  const int n0   = t16 * 4;
  const long mb  = (long)b * SEQ;
  const int c0   = c * CHUNK;

  float An[4];
#pragma unroll
  for (int i = 0; i < 4; ++i) An[i] = -__expf(A_log[n0 + i]);

  float4 pB4; float2 pB2;
  float pdt[2], pxc[2], pzs[2];

  auto ISSUE = [&](int cc) {
    const int row = tid >> 5;
    if constexpr (FINAL) {
      pB4 = ((const float4*)(xdbl + (mb + cc + row) * 128))[tid & 31];
    } else {
      pB2 = ((const float2*)(xdbl + (mb + cc + row) * 128))[tid & 31];
    }
#pragma unroll
    for (int j = 0; j < 2; ++j) {
      const int item = tid + j * 1024;
      const int s = item >> 6, dl2 = item & 63;
      const long m = mb + cc + s;
      pdt[j] = dtin[m];
      pxc[j] = bf2f(xconv[m * D_INNER + d0 + dl2]);
      if constexpr (FINAL) pzs[j] = bf2f(zsilu[m * D_INNER + d0 + dl2]);
    }
  };

  auto COMMIT = [&]() {
    const int row = tid >> 5;
    if constexpr (FINAL) {
      const int col4 = tid & 31;
      if (col4 < 16) *(float4*)&sB[row * 64 + col4 * 4] = pB4;
      else           *(float4*)&sC[row * 64 + (col4 - 16) * 4] = pB4;
    } else {
      *(float2*)&sB[row * 64 + (tid & 31) * 2] = pB2;
    }
#pragma unroll
    for (int j = 0; j < 2; ++j) {
      const int item = tid + j * 1024;
      const int s = item >> 6, dl2 = item & 63;
      const float xv = fmaf(pdt[j], dt_w[d0 + dl2], dt_b[d0 + dl2]);
      const float dtv = fmaxf(xv, 0.f) + __logf(1.f + __expf(-fabsf(xv)));
      if constexpr (FINAL)
        sp4[s * 64 + dl2] = (float4){dtv, dtv * pxc[j], D_param[d0 + dl2] * pxc[j], pzs[j]};
      else
        sp2[s * 64 + dl2] = (float2){dtv, dtv * pxc[j]};
    }
  };

  ISSUE(c0);
  COMMIT();
  __syncthreads();

  const long base = ((long)(b * NCHUNK + c) * D_INNER + d0 + dl) * 64 + n0;
  float h0, h1, h2, h3;
  if constexpr (FINAL) {
    const float4 S = *(const float4*)&Hbuf[base];
    h0 = S.x; h1 = S.y; h2 = S.z; h3 = S.w;
  } else {
    h0 = h1 = h2 = h3 = 0.f;
  }
  float Tsum = 0.f;

  for (int cs = 0; cs < CHUNK; cs += CH) {
    const bool more = (cs + CH < CHUNK);
    if (more) ISSUE(c0 + cs + CH);
#pragma unroll 4
    for (int s = 0; s < CH; ++s) {
      const float4 Bv = *(const float4*)&sB[s * 64 + n0];
      float dtv, q;
      float4 pk;
      if constexpr (FINAL) {
        pk = sp4[s * 64 + dl];
        dtv = pk.x; q = pk.y;
      } else {
        const float2 p2 = sp2[s * 64 + dl];
        dtv = p2.x; q = p2.y;
      }
      const float e0 = __expf(dtv * An[0]);
      const float e1 = __expf(dtv * An[1]);
      const float e2 = __expf(dtv * An[2]);
      const float e3 = __expf(dtv * An[3]);
      h0 = fmaf(h0, e0, q * Bv.x);
      h1 = fmaf(h1, e1, q * Bv.y);
      h2 = fmaf(h2, e2, q * Bv.z);
      h3 = fmaf(h3, e3, q * Bv.w);
      if constexpr (FINAL) {
        const float4 Cv = *(const float4*)&sC[s * 64 + n0];
        float p = fmaf(h3, Cv.w, fmaf(h2, Cv.z, fmaf(h1, Cv.y, h0 * Cv.x)));
        p += __shfl_xor(p, 1, 64);
        p += __shfl_xor(p, 2, 64);
        p += __shfl_xor(p, 4, 64);
        p += __shfl_xor(p, 8, 64);
        if (t16 == 0) sy[s * 64 + dl] = __float2bfloat16((p + pk.z) * pk.w);
      } else {
        Tsum += dtv;
      }
    }
    if constexpr (FINAL) {
      __syncthreads();
      // coalesced y-tile store: 32 rows x 128 B
      {
        const int row = tid >> 5, col2 = tid & 31;
        const uint32_t v = ((const uint32_t*)sy)[tid];
        *(uint32_t*)&ygated[(mb + c0 + cs + row) * (long)D_INNER + d0 + col2 * 2] = v;
      }
      if (more) { COMMIT(); __syncthreads(); }
    } else {
      if (more) { __syncthreads(); COMMIT(); __syncthreads(); }
    }
  }

  if constexpr (!FINAL) {
    *(float4*)&Hbuf[base] = (float4){h0, h1, h2, h3};
    if (t16 == 0) Tbuf[(b * NCHUNK + c) * D_INNER + d0 + dl] = Tsum;
  }
}

// ---------------------------------------------------------------------------
// Inter-chunk linkage: S_0 = 0; S_c = H_{c-1} + exp(An*T_{c-1}) * S_{c-1}.
// In place: Hbuf[c] <- S_c. One thread per (b, d, n4). 49152 threads.
// ---------------------------------------------------------------------------
__global__ __launch_bounds__(256) void scan_link(
    float* __restrict__ H, const float* __restrict__ Tbuf,
    const float* __restrict__ A_log)
{
  const int t = blockIdx.x * 256 + threadIdx.x;  // < 49152
  const int b = t / 24576;
  const int r = t % 24576;
  const int d = r >> 4;
  const int n4 = r & 15;
  float An[4];
#pragma unroll
  for (int i = 0; i < 4; ++i) An[i] = -__expf(A_log[n4 * 4 + i]);
  float4* H4 = (float4*)H;
  float4 S = {0.f, 0.f, 0.f, 0.f};
#pragma unroll
  for (int c = 0; c < NCHUNK; ++c) {
    const long i4 = ((long)(b * NCHUNK + c) * D_INNER + d) * 16 + n4;
    const float4 Hc = H4[i4];
    const float T = Tbuf[(b * NCHUNK + c) * D_INNER + d];
    H4[i4] = S;
    S.x = fmaf(__expf(An[0] * T), S.x, Hc.x);
    S.y = fmaf(__expf(An[1] * T), S.y, Hc.y);
    S.z = fmaf(__expf(An[2] * T), S.z, Hc.z);
    S.w = fmaf(__expf(An[3] * T), S.w, Hc.w);
  }
}

// ---------------------------------------------------------------------------
extern "C" void kernel_launch(void* const* d_in, const int* in_sizes, int n_in,
                              void* d_out, int out_size, void* d_ws, size_t ws_size,
                              hipStream_t stream)
{
  const float* x       = (const float*)d_in[0];
  const float* W_in    = (const float*)d_in[1];
  const float* conv_w  = (const float*)d_in[2];
  const float* conv_b  = (const float*)d_in[3];
  const float* W_x     = (const float*)d_in[4];
  const float* dt_w    = (const float*)d_in[5];
  const float* dt_b    = (const float*)d_in[6];
  const float* A_log   = (const float*)d_in[7];
  const float* D_param = (const float*)d_in[8];
  const float* W_out   = (const float*)d_in[9];
  float* out = (float*)d_out;

  char* ws = (char*)d_ws;
  bf16*  xzbf   = (bf16*)(ws);                     // 12,582,912
  bf16*  xconv  = (bf16*)(ws + 12582912);          // 6,291,456
  bf16*  zsilu  = (bf16*)(ws + 18874368);          // 6,291,456
  float* xdbl   = (float*)(ws + 25165824);         // 1,048,576
  float* dtin   = (float*)(ws + 26214400);         // 8,192
  float* Tbuf   = (float*)(ws + 26222592);         // 196,608
  float* Hbuf   = (float*)(ws + 26419200);         // 12,582,912
  bf16*  ygated = (bf16*)(ws + 39002112);          // 6,291,456
  bf16*  xbf    = (bf16*)(ws + 45293568);          // 3,145,728
  bf16*  Winbf  = (bf16*)(ws + 48439296);          // 4,718,592
  bf16*  Wxbf   = (bf16*)(ws + 53157888);          // 393,216
  bf16*  Woutbf = (bf16*)(ws + 53551104);          // 2,359,296 (end 55,910,400)

  // zero-init accumulators (dtin atomic, xdbl split-K atomic)
  hipMemsetAsync(dtin, 0, M_TOK * sizeof(float), stream);
  hipMemsetAsync(xdbl, 0, M_TOK * 128 * sizeof(float), stream);

  // 0) fp32->bf16 operand conversions
  cvt_all<<<5184, 256, 0, stream>>>(x, W_in, W_x + D_INNER, W_out,
                                    xbf, Winbf, Wxbf, Woutbf);

  // 1) xz = x @ W_in^T  (M=2048,N=3072,K=768) -> bf16
  gemm_bt<128, 128, 1, bf16><<<dim3(24, 16), 256, 0, stream>>>(
      xbf, Winbf, xzbf, M_TOK, 2 * D_INNER, D_MODEL);

  // 2) conv + silu + silu(z) + fused dtin reduction
  conv_silu<<<(M_TOK * D_INNER) / 256, 256, 0, stream>>>(
      xzbf, conv_w, conv_b, W_x, xconv, zsilu, dtin);

  // 3) B,C = xconv @ W_x[1:129]^T  (M=2048,N=128,K=1536), split-K=4 atomics
  gemm_bt<64, 64, 4, float><<<dim3(2, 32, 4), 256, 0, stream>>>(
      xconv, Wxbf, xdbl, M_TOK, 128, D_INNER);

  // 4) chunked selective scan (3 passes)
  scan_chunk<false><<<dim3(24, NCHUNK, 2), 1024, 24576, stream>>>(
      xdbl, dtin, xconv, nullptr, A_log, nullptr, dt_w, dt_b,
      Hbuf, Tbuf, nullptr);
  scan_link<<<192, 256, 0, stream>>>(Hbuf, Tbuf, A_log);
  scan_chunk<true><<<dim3(24, NCHUNK, 2), 1024, 53248, stream>>>(
      xdbl, dtin, xconv, zsilu, A_log, D_param, dt_w, dt_b,
      Hbuf, nullptr, ygated);

  // 5) out = ygated @ W_out^T  (M=2048,N=768,K=1536) -> fp32 d_out
  gemm_bt<64, 64, 1, float><<<dim3(12, 32), 256, 0, stream>>>(
      ygated, Woutbf, out, M_TOK, D_MODEL, D_INNER);
}